// Round 18
// baseline (125.749 us; speedup 1.0000x reference)
//
#include <hip/hip_runtime.h>
#include <hip/hip_bf16.h>

typedef unsigned short ushort_t;
typedef unsigned int uint_t;
typedef __attribute__((ext_vector_type(4))) float f32x4;
typedef __attribute__((ext_vector_type(16))) float f32x16;
typedef __attribute__((ext_vector_type(8))) short short8;
typedef __attribute__((ext_vector_type(4))) short short4x;
typedef __attribute__((ext_vector_type(4))) unsigned short u16x4;
typedef __attribute__((ext_vector_type(2))) uint_t u32x2;

typedef const __attribute__((address_space(1))) unsigned char glob_t;
typedef __attribute__((address_space(3))) unsigned char lds_t;

#define S_LEN 2048
#define DM 1024
#define NH 16
#define DH 64
#define NB 2
#define BH (NB*NH)          // 32
#define MROWS (NB*S_LEN)    // 4096

#define SCALE_L2E 0.18033688f   /* 0.125 * log2(e) — folded into Q */

__device__ __forceinline__ float bf2f(ushort_t u) {
    return __uint_as_float(((uint_t)u) << 16);
}
__device__ __forceinline__ ushort_t f2bf(float f) {
    __hip_bfloat16 h = __float2bfloat16(f);
    return *reinterpret_cast<ushort_t*>(&h);
}

// ---------------------------------------------------------------- prep
__global__ __launch_bounds__(256) void prep_all(
    const float* __restrict__ X,  const float* __restrict__ Wq,
    const float* __restrict__ Wk, const float* __restrict__ Wv,
    const float* __restrict__ Wo, const int* __restrict__ pos,
    ushort_t* __restrict__ Xb,  ushort_t* __restrict__ Wqb,
    ushort_t* __restrict__ Wkb, ushort_t* __restrict__ Wvb,
    ushort_t* __restrict__ Wob, float2* __restrict__ tab)
{
    int bid = blockIdx.x;
    if (bid < 8192) {
        size_t i = (size_t)bid * 256 + threadIdx.x;
        size_t e = i * 4;
        const float* src; ushort_t* dst; size_t off;
        if (e < (size_t)MROWS * DM) { src = X; dst = Xb; off = e; }
        else {
            size_t r = e - (size_t)MROWS * DM;
            int w = (int)(r >> 20); off = r & 1048575;
            src = (w == 0) ? Wq : (w == 1) ? Wk : (w == 2) ? Wv : Wo;
            dst = (w == 0) ? Wqb : (w == 1) ? Wkb : (w == 2) ? Wvb : Wob;
        }
        float4 v = *reinterpret_cast<const float4*>(src + off);
        u16x4 o;
        o[0] = f2bf(v.x); o[1] = f2bf(v.y); o[2] = f2bf(v.z); o[3] = f2bf(v.w);
        *reinterpret_cast<u16x4*>(dst + off) = o;
    } else {
        int i = (bid - 8192) * 256 + threadIdx.x;   // 65536
        int s = i >> 5, f = i & 31;
        float inv = powf(10000.0f, -(float)f / 32.0f);
        float ang = (float)pos[s] * inv;
        tab[i] = make_float2(cosf(ang), sinf(ang));
    }
}

// ---------------------------------------------------------------- GEMM
// (verbatim R11 gemm128b) C[m][n] = sum_k A[m][k]*W[n][k]; BK=32,
// m97-style global_load_lds staging, linear LDS.
template<int MODE>
__global__ __launch_bounds__(256) void gemm128b(
    const ushort_t* __restrict__ A,
    const ushort_t* __restrict__ W0, const ushort_t* __restrict__ W1,
    const ushort_t* __restrict__ W2,
    ushort_t* __restrict__ D0, ushort_t* __restrict__ D1,
    ushort_t* __restrict__ D2,
    float* __restrict__ Fout, const float2* __restrict__ tab)
{
    __shared__ __attribute__((aligned(16))) ushort_t As[128 * 32];
    __shared__ __attribute__((aligned(16))) ushort_t Bs[128 * 32];
    const ushort_t* W = (MODE == 1 || blockIdx.z == 0) ? W0
                        : (blockIdx.z == 1 ? W1 : W2);
    ushort_t* Dst = (blockIdx.z == 0) ? D0 : (blockIdx.z == 1) ? D1 : D2;
    int m0 = blockIdx.x * 128, n0 = blockIdx.y * 128;
    int tid = threadIdx.x, lane = tid & 63, wv = tid >> 6;
    int wm = wv >> 1, wn = wv & 1;
    int l15 = lane & 15, g = lane >> 4;

    f32x4 acc[4][4];
    for (int i = 0; i < 4; i++)
        for (int j = 0; j < 4; j++)
            acc[i][j] = (f32x4){0.f, 0.f, 0.f, 0.f};

    int srow = wv * 32 + (lane >> 2);
    int scol = (lane & 3) * 8;
    const ushort_t* Ap = A + (size_t)(m0 + srow) * DM + scol;
    const ushort_t* Wp = W + (size_t)(n0 + srow) * DM + scol;
    lds_t* laA0 = (lds_t*)&As[wv * 1024];
    lds_t* laA1 = (lds_t*)&As[wv * 1024 + 512];
    lds_t* laB0 = (lds_t*)&Bs[wv * 1024];
    lds_t* laB1 = (lds_t*)&Bs[wv * 1024 + 512];

    for (int kk = 0; kk < DM; kk += 32) {
        __builtin_amdgcn_global_load_lds((glob_t*)(Ap + kk), laA0, 16, 0, 0);
        __builtin_amdgcn_global_load_lds((glob_t*)(Ap + 16 * DM + kk), laA1, 16, 0, 0);
        __builtin_amdgcn_global_load_lds((glob_t*)(Wp + kk), laB0, 16, 0, 0);
        __builtin_amdgcn_global_load_lds((glob_t*)(Wp + 16 * DM + kk), laB1, 16, 0, 0);
        __syncthreads();
        short8 af[4], bf[4];
        for (int i = 0; i < 4; i++)
            af[i] = *reinterpret_cast<const short8*>(
                &As[(wm * 64 + i * 16 + l15) * 32 + g * 8]);
        for (int j = 0; j < 4; j++)
            bf[j] = *reinterpret_cast<const short8*>(
                &Bs[(wn * 64 + j * 16 + l15) * 32 + g * 8]);
        __builtin_amdgcn_s_setprio(1);
        for (int i = 0; i < 4; i++)
            for (int j = 0; j < 4; j++)
                acc[i][j] = __builtin_amdgcn_mfma_f32_16x16x32_bf16(
                    af[i], bf[j], acc[i][j], 0, 0, 0);
        __builtin_amdgcn_s_setprio(0);
        __syncthreads();
    }

    for (int i = 0; i < 4; i++) {
        for (int j = 0; j < 4; j++) {
            int mbase = m0 + wm * 64 + i * 16 + g * 4;
            int n = n0 + wn * 64 + j * 16 + l15;
            if (MODE == 0) {
                int h = n >> 6, d = n & 63;
                if (blockIdx.z < 2) {
                    int f = d >> 1;
                    float sgn = (d & 1) ? 1.f : -1.f;
                    float sc = (blockIdx.z == 0) ? SCALE_L2E : 1.0f;
                    for (int r = 0; r < 4; r++) {
                        int m = mbase + r;
                        int b = m >> 11, s = m & 2047;
                        float v = acc[i][j][r];
                        float p = __shfl_xor(v, 1);
                        float2 cs = tab[s * 32 + f];
                        float out = (v * cs.x + p * cs.y * sgn) * sc;
                        Dst[(((size_t)(b * NH + h)) * S_LEN + s) * DH + d] =
                            f2bf(out);
                    }
                } else {
                    for (int r = 0; r < 4; r++) {
                        int m = mbase + r;
                        int b = m >> 11, s = m & 2047;
                        Dst[((size_t)(b * NH + h) * DH + d) * S_LEN + s] =
                            f2bf(acc[i][j][r]);
                    }
                }
            } else {
                for (int r = 0; r < 4; r++)
                    Fout[(size_t)(mbase + r) * DM + n] = acc[i][j][r];
            }
        }
    }
}

// ---------------------------------------------------------------- attention
// R17 structure (8-wave key-split, double-buffered KVBLK=128, 64KB LDS,
// 2 blocks/CU via launch_bounds(512,4)) with PER-SUBTILE round body to
// kill the R17 spill: QK->mask->softmax->PV completed for s=0 before s=1
// starts. Peak live regs ~63 (st 16 not 32, pa 4 not 8, kf dead before
// vb) -> fits the 64-arch-VGPR budget, WRITE_SIZE back to ~8MB.
// Freeze-max at (t==0, s==0): safe because for any computed wave
// k0 <= qmin (64-aligned k0 <= 32-aligned qmin+31 => k0 <= qmin), so key
// k0 (in subtile 0) is unmasked for every row -> frozen ref is a genuine
// score. Mask trigger per-subtile. Merge epilogue verbatim R17.
#define WAITV0 asm volatile("s_waitcnt vmcnt(0)" ::: "memory")

__global__ __launch_bounds__(512, 4) void attn_k16(
    const ushort_t* __restrict__ Q, const ushort_t* __restrict__ K,
    const ushort_t* __restrict__ Vt, ushort_t* __restrict__ O)
{
    __shared__ __attribute__((aligned(16))) ushort_t Ks[2][8192];  // 16KB ea
    __shared__ __attribute__((aligned(16))) ushort_t Vs[2][8192];  // 16KB ea

    int tid = threadIdx.x, wv = tid >> 6, lane = tid & 63;
    int l31 = lane & 31, h = lane >> 5, r7 = l31 & 7;
    int bid = blockIdx.x;
    int u = (bid < 256) ? (15 - (bid >> 5)) : ((bid - 256) >> 5);
    int bh = bid & 31;              // low bits -> XCD affinity for K/V reuse
    int qsub = wv & 3, hf = wv >> 2;
    int qmin = u * 128 + qsub * 32, qmax = qmin + 31;
    int ntr = u + 1;                // 128-key rounds

    const ushort_t* Qp = Q + (size_t)bh * S_LEN * DH;
    const char* Kp = (const char*)(K + (size_t)bh * S_LEN * DH);
    const char* Vp = (const char*)(Vt + (size_t)bh * DH * S_LEN);

    short8 qf[4];
    {
        const ushort_t* qp = Qp + (((size_t)(qmin + l31)) << 6) + h * 8;
        #pragma unroll
        for (int ds = 0; ds < 4; ds++)
            qf[ds] = *reinterpret_cast<const short8*>(qp + ds * 16);
    }

    f32x16 oacc[2];
    oacc[0] = (f32x16){0.f};
    oacc[1] = (f32x16){0.f};
    float m_run = -1e20f, l_run = 0.f;

#define STAGE17(buf, kk0) do {                                                \
    _Pragma("unroll") for (int c_ = 0; c_ < 2; ++c_) {                        \
        int L_ = c_ * 8192 + tid * 16;                                        \
        int rk_ = L_ >> 7;                                                    \
        int ck_ = (L_ & 127) ^ ((rk_ & 7) << 4);                              \
        __builtin_amdgcn_global_load_lds(                                     \
            (glob_t*)(Kp + (size_t)((kk0) + rk_) * 128 + ck_),                \
            (lds_t*)((char*)&Ks[buf][0] + c_ * 8192 + wv * 1024), 16, 0, 0);  \
        int rv_ = L_ >> 8;                                                    \
        int cb_ = L_ & 255;                                                   \
        int cv_ = ((cb_ & 127) ^ ((rv_ & 7) << 4)) | (cb_ & 128);             \
        __builtin_amdgcn_global_load_lds(                                     \
            (glob_t*)(Vp + (size_t)rv_ * (S_LEN * 2) + (size_t)(kk0) * 2      \
                      + cv_),                                                 \
            (lds_t*)((char*)&Vs[buf][0] + c_ * 8192 + wv * 1024), 16, 0, 0);  \
    } } while (0)

    STAGE17(0, 0);
    WAITV0;
    __builtin_amdgcn_s_barrier();

    int buf = 0;
    for (int t = 0; t < ntr; ++t) {
        if (t + 1 < ntr) STAGE17(buf ^ 1, (t + 1) * 128);

        int k0 = t * 128 + hf * 64;
        if (k0 <= qmax) {
            const char* kb = (const char*)&Ks[buf][0];
            const char* vbp = (const char*)&Vs[buf][0];
            float ps = 0.f;

            #pragma unroll
            for (int s = 0; s < 2; s++) {
                // ---- QK^T for this 32-key subtile
                short8 kf[4];
                #pragma unroll
                for (int ds = 0; ds < 4; ds++)
                    kf[ds] = *reinterpret_cast<const short8*>(
                        kb + (hf * 64 + s * 32 + l31) * 128
                        + (((h + 2 * ds) ^ r7) << 4));
                __builtin_amdgcn_s_setprio(1);
                f32x16 z = {0.f};
                #pragma unroll
                for (int ds = 0; ds < 4; ds++)
                    z = __builtin_amdgcn_mfma_f32_32x32x16_bf16(
                        kf[ds], qf[ds], z, 0, 0, 0);
                __builtin_amdgcn_s_setprio(0);

                // ---- causal mask (per-subtile trigger)
                if (k0 + s * 32 + 31 > qmin) {
                    int q = qmin + l31;
                    #pragma unroll
                    for (int r = 0; r < 16; r++)
                        if ((k0 + s * 32 + (r & 3) + 8 * (r >> 2) + 4 * h) > q)
                            z[r] = -1e30f;
                }

                // ---- one-time frozen max (t==0, s==0; key k0 unmasked
                // for every row => genuine score reference)
                if (t == 0 && s == 0) {
                    float mv = z[0];
                    #pragma unroll
                    for (int r = 1; r < 16; r++) mv = fmaxf(mv, z[r]);
                    mv = fmaxf(mv, __shfl_xor(mv, 32));
                    m_run = mv + 8.0f;
                }

                // ---- exp2 softmax (frozen ref), pack to PV B-operand
                short4x pa[4];
                #pragma unroll
                for (int kt = 0; kt < 4; kt++) {
                    float p0 = exp2f(z[4 * kt + 0] - m_run);
                    float p1 = exp2f(z[4 * kt + 1] - m_run);
                    float p2 = exp2f(z[4 * kt + 2] - m_run);
                    float p3 = exp2f(z[4 * kt + 3] - m_run);
                    ps += (p0 + p1) + (p2 + p3);
                    u32x2 w = { (uint_t)f2bf(p0) | ((uint_t)f2bf(p1) << 16),
                                (uint_t)f2bf(p2) | ((uint_t)f2bf(p3) << 16) };
                    pa[kt] = __builtin_bit_cast(short4x, w);
                }

                // ---- PV (zero-shuffle)
                short4x vb[2][4];
                #pragma unroll
                for (int db = 0; db < 2; db++)
                    #pragma unroll
                    for (int kt = 0; kt < 4; kt++) {
                        int c = s * 4 + kt;   // 16B unit within 128B half
                        vb[db][kt] = *reinterpret_cast<const short4x*>(
                            vbp + (db * 32 + l31) * 256 + hf * 128
                            + (((c ^ r7) & 7) << 4) + h * 8);
                    }
                __builtin_amdgcn_s_setprio(1);
                #pragma unroll
                for (int kt = 0; kt < 4; kt++) {
                    oacc[0] = __builtin_amdgcn_mfma_f32_32x32x8bf16_1k(
                        vb[0][kt], pa[kt], oacc[0], 0, 0, 0);
                    oacc[1] = __builtin_amdgcn_mfma_f32_32x32x8bf16_1k(
                        vb[1][kt], pa[kt], oacc[1], 0, 0, 0);
                }
                __builtin_amdgcn_s_setprio(0);
            }
            l_run += ps;
        }

        WAITV0;                       // stage(t+1) landed (issued pre-compute)
        __builtin_amdgcn_s_barrier();
        buf ^= 1;
    }

    // ---- cross-wave merge: hf=1 publishes, hf=0 merges + stores (exact)
    {
        float* smK = (float*)&Ks[0][0];        // 32KB scratch (loop done)
        float* smV = (float*)&Vs[0][0];        // 32KB scratch
        float* base = (qsub < 2) ? smK : smV;
        float* slot = base + ((qsub & 1) * 64 + lane) * 34;
        if (hf == 1) {
            #pragma unroll
            for (int j = 0; j < 16; j++) slot[j] = oacc[0][j];
            #pragma unroll
            for (int j = 0; j < 16; j++) slot[16 + j] = oacc[1][j];
            slot[32] = l_run;
            slot[33] = m_run;
        }
        __syncthreads();
        if (hf == 0) {
            float lB = slot[32], mB = slot[33];
            float ms = fmaxf(m_run, mB);
            float fa = exp2f(m_run - ms), fb = exp2f(mB - ms);
            float l_tot = l_run * fa + lB * fb;
            l_tot += __shfl_xor(l_tot, 32);
            float inv = 1.0f / l_tot;
            int b = bh >> 4, head = bh & 15;
            int q_row = qmin + l31;
            size_t obase = ((size_t)b * S_LEN + q_row) * DM + head * DH;
            #pragma unroll
            for (int db = 0; db < 2; db++)
                #pragma unroll
                for (int rg = 0; rg < 4; rg++) {
                    u16x4 o;
                    #pragma unroll
                    for (int j = 0; j < 4; j++) {
                        float v = oacc[db][rg * 4 + j] * fa
                                + slot[db * 16 + rg * 4 + j] * fb;
                        o[j] = f2bf(v * inv);
                    }
                    *reinterpret_cast<u16x4*>(
                        &O[obase + db * 32 + rg * 8 + h * 4]) = o;
                }
        }
    }
#undef STAGE17
}

// ---------------------------------------------------------------- launch
extern "C" void kernel_launch(void* const* d_in, const int* in_sizes, int n_in,
                              void* d_out, int out_size, void* d_ws, size_t ws_size,
                              hipStream_t stream)
{
    const float* X  = (const float*)d_in[0];
    const int* pos  = (const int*)d_in[1];
    const float* qw = (const float*)d_in[2];
    const float* kw = (const float*)d_in[3];
    const float* vw = (const float*)d_in[4];
    const float* ow = (const float*)d_in[5];
    float* out = (float*)d_out;

    char* ws = (char*)d_ws;
    ushort_t* Xb   = (ushort_t*)(ws);               //  8 MB  X bf16
    ushort_t* Wqb  = (ushort_t*)(ws + 8388608);     //  2 MB
    ushort_t* Wkb  = (ushort_t*)(ws + 10485760);    //  2 MB
    ushort_t* Wvb  = (ushort_t*)(ws + 12582912);    //  2 MB
    ushort_t* Wob  = (ushort_t*)(ws + 14680064);    //  2 MB
    ushort_t* Qbh  = (ushort_t*)(ws + 16777216);    //  8 MB [BH][S][64]
    ushort_t* Kbh  = (ushort_t*)(ws + 25165824);    //  8 MB
    ushort_t* Vtb  = (ushort_t*)(ws + 41943040);    //  8 MB [BH][64][S]
    ushort_t* AttO = (ushort_t*)(ws + 50331648);    //  8 MB [B][S][1024]
    float2*   tab  = (float2*)(ws + 58720256);      //  0.5 MB

    prep_all<<<8448, 256, 0, stream>>>(X, qw, kw, vw, ow, pos,
                                       Xb, Wqb, Wkb, Wvb, Wob, tab);
    gemm128b<0><<<dim3(32, 8, 3), 256, 0, stream>>>(
        Xb, Wqb, Wkb, Wvb, Qbh, Kbh, Vtb, nullptr, tab);
    attn_k16<<<512, 512, 0, stream>>>(Qbh, Kbh, Vtb, AttO);
    gemm128b<1><<<dim3(32, 8, 1), 256, 0, stream>>>(
        AttO, Wob, nullptr, nullptr, nullptr, nullptr, nullptr, out, tab);
}

// Round 20
// 125.372 us; speedup vs baseline: 1.0030x; 1.0030x over previous
//
#include <hip/hip_runtime.h>
#include <hip/hip_bf16.h>

typedef unsigned short ushort_t;
typedef unsigned int uint_t;
typedef __attribute__((ext_vector_type(4))) float f32x4;
typedef __attribute__((ext_vector_type(16))) float f32x16;
typedef __attribute__((ext_vector_type(8))) short short8;
typedef __attribute__((ext_vector_type(4))) short short4x;
typedef __attribute__((ext_vector_type(4))) unsigned short u16x4;
typedef __attribute__((ext_vector_type(2))) uint_t u32x2;

typedef const __attribute__((address_space(1))) unsigned char glob_t;
typedef __attribute__((address_space(3))) unsigned char lds_t;

#define S_LEN 2048
#define DM 1024
#define NH 16
#define DH 64
#define NB 2
#define BH (NB*NH)          // 32
#define MROWS (NB*S_LEN)    // 4096

#define SCALE_L2E 0.18033688f   /* 0.125 * log2(e) — folded into Q */

__device__ __forceinline__ float bf2f(ushort_t u) {
    return __uint_as_float(((uint_t)u) << 16);
}
__device__ __forceinline__ ushort_t f2bf(float f) {
    __hip_bfloat16 h = __float2bfloat16(f);
    return *reinterpret_cast<ushort_t*>(&h);
}

#define WAITV0 asm volatile("s_waitcnt vmcnt(0)" ::: "memory")
#define WAITV2 asm volatile("s_waitcnt vmcnt(2)" ::: "memory")

// ---------------------------------------------------------------- prep
__global__ __launch_bounds__(256) void prep_all(
    const float* __restrict__ X,  const float* __restrict__ Wq,
    const float* __restrict__ Wk, const float* __restrict__ Wv,
    const float* __restrict__ Wo, const int* __restrict__ pos,
    ushort_t* __restrict__ Xb,  ushort_t* __restrict__ Wqb,
    ushort_t* __restrict__ Wkb, ushort_t* __restrict__ Wvb,
    ushort_t* __restrict__ Wob, float2* __restrict__ tab)
{
    int bid = blockIdx.x;
    if (bid < 8192) {
        size_t i = (size_t)bid * 256 + threadIdx.x;
        size_t e = i * 4;
        const float* src; ushort_t* dst; size_t off;
        if (e < (size_t)MROWS * DM) { src = X; dst = Xb; off = e; }
        else {
            size_t r = e - (size_t)MROWS * DM;
            int w = (int)(r >> 20); off = r & 1048575;
            src = (w == 0) ? Wq : (w == 1) ? Wk : (w == 2) ? Wv : Wo;
            dst = (w == 0) ? Wqb : (w == 1) ? Wkb : (w == 2) ? Wvb : Wob;
        }
        float4 v = *reinterpret_cast<const float4*>(src + off);
        u16x4 o;
        o[0] = f2bf(v.x); o[1] = f2bf(v.y); o[2] = f2bf(v.z); o[3] = f2bf(v.w);
        *reinterpret_cast<u16x4*>(dst + off) = o;
    } else {
        int i = (bid - 8192) * 256 + threadIdx.x;   // 65536
        int s = i >> 5, f = i & 31;
        float inv = powf(10000.0f, -(float)f / 32.0f);
        float ang = (float)pos[s] * inv;
        tab[i] = make_float2(cosf(ang), sinf(ang));
    }
}

// ---------------------------------------------------------------- QKV GEMM
// Fused QKV: C[m][n] = sum_k Xb[m][k] * W3[n][k], M=4096, N=3072, K=1024.
// 256x256 tile, BK=64, 8 waves (2M x 4N), 8-phase counted-vmcnt schedule
// (T3+T4) with T2 XOR-swizzled LDS. A/B tiles split into 128-row halves,
// each half double-buffered by K-tile parity. Per phase: {frag ds_reads,
// one half-tile stage (2 gl_lds), barrier, 16 MFMA (setprio), barrier}.
// Stage windows from half-tile death: B(T) dies after q0, A(T) after q3:
//   ph1:A0(T+1) ph2:A1(T+1)+B0(T+2) ph3:B1(T+2)
//   ph5:A0(T+2) ph6:A1(T+2)+B0(T+3) ph7:B1(T+3)
// vmcnt(2) at ph4/ph8 only (vmcnt(0) final iteration). Epilogue: RoPE'd
// Q/K scatter + V transposed scatter (validated gemm128b logic).
__global__ __launch_bounds__(512, 2) void qkv8_gemm(
    const ushort_t* __restrict__ A, const ushort_t* __restrict__ W3,
    ushort_t* __restrict__ Qd, ushort_t* __restrict__ Kd,
    ushort_t* __restrict__ Vtd, const float2* __restrict__ tab)
{
    __shared__ __attribute__((aligned(16))) ushort_t As[2][2][8192]; // 64KB
    __shared__ __attribute__((aligned(16))) ushort_t Bs[2][2][8192]; // 64KB

    int tid = threadIdx.x, wv = tid >> 6, lane = tid & 63;
    int l15 = lane & 15, g = lane >> 4;
    int wm = wv >> 2, wn = wv & 3, wbh = wn >> 1;
    int m0 = blockIdx.x * 256, n0 = blockIdx.y * 256;
    int swz = (l15 & 7) << 4;
    const char* Ab = (const char*)A;
    const char* Wb = (const char*)W3;

    f32x4 acc[8][4];
    #pragma unroll
    for (int i = 0; i < 8; i++)
        #pragma unroll
        for (int j = 0; j < 4; j++)
            acc[i][j] = (f32x4){0.f, 0.f, 0.f, 0.f};

#define STG_A(hh, t) do {                                                     \
    _Pragma("unroll") for (int c_ = 0; c_ < 2; ++c_) {                        \
        int L_ = c_ * 8192 + tid * 16;                                        \
        int row_ = L_ >> 7;                                                   \
        int cb_ = (L_ & 127) ^ ((row_ & 7) << 4);                             \
        __builtin_amdgcn_global_load_lds(                                     \
            (glob_t*)(Ab + ((size_t)(m0 + (hh) * 128 + row_) * DM             \
                      + (t) * 64) * 2 + cb_),                                 \
            (lds_t*)((char*)&As[hh][(t) & 1][0] + c_ * 8192 + wv * 1024),     \
            16, 0, 0);                                                        \
    } } while (0)
#define STG_B(hh, t) do {                                                     \
    _Pragma("unroll") for (int c_ = 0; c_ < 2; ++c_) {                        \
        int L_ = c_ * 8192 + tid * 16;                                        \
        int row_ = L_ >> 7;                                                   \
        int cb_ = (L_ & 127) ^ ((row_ & 7) << 4);                             \
        __builtin_amdgcn_global_load_lds(                                     \
            (glob_t*)(Wb + ((size_t)(n0 + (hh) * 128 + row_) * DM             \
                      + (t) * 64) * 2 + cb_),                                 \
            (lds_t*)((char*)&Bs[hh][(t) & 1][0] + c_ * 8192 + wv * 1024),     \
            16, 0, 0);                                                        \
    } } while (0)

    short8 bf[4][2];
#define DO_PHASE(t, q, STAGES, WCNT) do {                                     \
    const char* ab_ = (const char*)&As[wm][(t) & 1][0];                       \
    const char* bb_ = (const char*)&Bs[wbh][(t) & 1][0];                      \
    if ((q) == 0) {                                                           \
        _Pragma("unroll") for (int j_ = 0; j_ < 4; ++j_)                      \
        _Pragma("unroll") for (int ks_ = 0; ks_ < 2; ++ks_)                   \
            bf[j_][ks_] = *reinterpret_cast<const short8*>(                   \
                bb_ + ((wn & 1) * 64 + j_ * 16 + l15) * 128                   \
                + ((ks_ * 64 + g * 16) ^ swz));                               \
    }                                                                         \
    short8 af_[2][2];                                                         \
    _Pragma("unroll") for (int ii_ = 0; ii_ < 2; ++ii_)                       \
    _Pragma("unroll") for (int ks_ = 0; ks_ < 2; ++ks_)                       \
        af_[ii_][ks_] = *reinterpret_cast<const short8*>(                     \
            ab_ + (((q) * 2 + ii_) * 16 + l15) * 128                          \
            + ((ks_ * 64 + g * 16) ^ swz));                                   \
    STAGES;                                                                   \
    __builtin_amdgcn_s_barrier();                                             \
    __builtin_amdgcn_s_setprio(1);                                            \
    _Pragma("unroll") for (int ii_ = 0; ii_ < 2; ++ii_)                       \
    _Pragma("unroll") for (int j_ = 0; j_ < 4; ++j_)                          \
    _Pragma("unroll") for (int ks_ = 0; ks_ < 2; ++ks_)                       \
        acc[(q) * 2 + ii_][j_] = __builtin_amdgcn_mfma_f32_16x16x32_bf16(     \
            af_[ii_][ks_], bf[j_][ks_], acc[(q) * 2 + ii_][j_], 0, 0, 0);     \
    __builtin_amdgcn_s_setprio(0);                                            \
    WCNT;                                                                     \
    __builtin_amdgcn_s_barrier();                                             \
} while (0)

    // prologue: A(0), B(0), B(1) staged; full drain
    STG_A(0, 0); STG_A(1, 0);
    STG_B(0, 0); STG_B(1, 0);
    STG_B(0, 1); STG_B(1, 1);
    WAITV0;
    __builtin_amdgcn_s_barrier();

    for (int I = 0; I < 8; ++I) {
        int T = 2 * I;
        bool more = (I < 7);              // T+2,T+3 exist iff more
        // ---- tile T (even parity)
        DO_PHASE(T, 0, { STG_A(0, T + 1); }, {});
        DO_PHASE(T, 1, { STG_A(1, T + 1); if (more) STG_B(0, T + 2); }, {});
        DO_PHASE(T, 2, { if (more) STG_B(1, T + 2); }, {});
        DO_PHASE(T, 3, {}, { if (more) { WAITV2; } else { WAITV0; } });
        // ---- tile T+1 (odd parity)
        DO_PHASE(T + 1, 0, { if (more) STG_A(0, T + 2); }, {});
        DO_PHASE(T + 1, 1, { if (more) { STG_A(1, T + 2); STG_B(0, T + 3); } }, {});
        DO_PHASE(T + 1, 2, { if (more) STG_B(1, T + 3); }, {});
        DO_PHASE(T + 1, 3, {}, { if (more) { WAITV2; } else { WAITV0; } });
    }
    WAITV0;   // safety drain before LDS lifetime ends

    // ---- epilogue: RoPE'd Q/K scatter + V transposed scatter
    #pragma unroll
    for (int i = 0; i < 8; i++) {
        #pragma unroll
        for (int j = 0; j < 4; j++) {
            int mb = m0 + wm * 128 + i * 16 + g * 4;
            int n = n0 + wn * 64 + j * 16 + l15;
            int w = n >> 10, rem = n & 1023;
            int hh = rem >> 6, d = rem & 63;
            if (w < 2) {
                int f = d >> 1;
                float sgn = (d & 1) ? 1.f : -1.f;
                float sc = (w == 0) ? SCALE_L2E : 1.0f;
                ushort_t* Dst = (w == 0) ? Qd : Kd;
                #pragma unroll
                for (int r = 0; r < 4; r++) {
                    int m = mb + r;
                    int b = m >> 11, s = m & 2047;
                    float v = acc[i][j][r];
                    float p = __shfl_xor(v, 1);
                    float2 cs = tab[s * 32 + f];
                    Dst[(((size_t)(b * NH + hh)) * S_LEN + s) * DH + d] =
                        f2bf((v * cs.x + p * cs.y * sgn) * sc);
                }
            } else {
                #pragma unroll
                for (int r = 0; r < 4; r++) {
                    int m = mb + r;
                    int b = m >> 11, s = m & 2047;
                    Vtd[((size_t)(b * NH + hh) * DH + d) * S_LEN + s] =
                        f2bf(acc[i][j][r]);
                }
            }
        }
    }
#undef DO_PHASE
#undef STG_A
#undef STG_B
}

// ---------------------------------------------------------------- GEMM
// (verbatim R11 gemm128b) — used for O-proj (MODE 1)
template<int MODE>
__global__ __launch_bounds__(256) void gemm128b(
    const ushort_t* __restrict__ A,
    const ushort_t* __restrict__ W0, const ushort_t* __restrict__ W1,
    const ushort_t* __restrict__ W2,
    ushort_t* __restrict__ D0, ushort_t* __restrict__ D1,
    ushort_t* __restrict__ D2,
    float* __restrict__ Fout, const float2* __restrict__ tab)
{
    __shared__ __attribute__((aligned(16))) ushort_t As[128 * 32];
    __shared__ __attribute__((aligned(16))) ushort_t Bs[128 * 32];
    const ushort_t* W = (MODE == 1 || blockIdx.z == 0) ? W0
                        : (blockIdx.z == 1 ? W1 : W2);
    ushort_t* Dst = (blockIdx.z == 0) ? D0 : (blockIdx.z == 1) ? D1 : D2;
    int m0 = blockIdx.x * 128, n0 = blockIdx.y * 128;
    int tid = threadIdx.x, lane = tid & 63, wv = tid >> 6;
    int wm = wv >> 1, wn = wv & 1;
    int l15 = lane & 15, g = lane >> 4;

    f32x4 acc[4][4];
    for (int i = 0; i < 4; i++)
        for (int j = 0; j < 4; j++)
            acc[i][j] = (f32x4){0.f, 0.f, 0.f, 0.f};

    int srow = wv * 32 + (lane >> 2);
    int scol = (lane & 3) * 8;
    const ushort_t* Ap = A + (size_t)(m0 + srow) * DM + scol;
    const ushort_t* Wp = W + (size_t)(n0 + srow) * DM + scol;
    lds_t* laA0 = (lds_t*)&As[wv * 1024];
    lds_t* laA1 = (lds_t*)&As[wv * 1024 + 512];
    lds_t* laB0 = (lds_t*)&Bs[wv * 1024];
    lds_t* laB1 = (lds_t*)&Bs[wv * 1024 + 512];

    for (int kk = 0; kk < DM; kk += 32) {
        __builtin_amdgcn_global_load_lds((glob_t*)(Ap + kk), laA0, 16, 0, 0);
        __builtin_amdgcn_global_load_lds((glob_t*)(Ap + 16 * DM + kk), laA1, 16, 0, 0);
        __builtin_amdgcn_global_load_lds((glob_t*)(Wp + kk), laB0, 16, 0, 0);
        __builtin_amdgcn_global_load_lds((glob_t*)(Wp + 16 * DM + kk), laB1, 16, 0, 0);
        __syncthreads();
        short8 af[4], bf[4];
        for (int i = 0; i < 4; i++)
            af[i] = *reinterpret_cast<const short8*>(
                &As[(wm * 64 + i * 16 + l15) * 32 + g * 8]);
        for (int j = 0; j < 4; j++)
            bf[j] = *reinterpret_cast<const short8*>(
                &Bs[(wn * 64 + j * 16 + l15) * 32 + g * 8]);
        __builtin_amdgcn_s_setprio(1);
        for (int i = 0; i < 4; i++)
            for (int j = 0; j < 4; j++)
                acc[i][j] = __builtin_amdgcn_mfma_f32_16x16x32_bf16(
                    af[i], bf[j], acc[i][j], 0, 0, 0);
        __builtin_amdgcn_s_setprio(0);
        __syncthreads();
    }

    for (int i = 0; i < 4; i++) {
        for (int j = 0; j < 4; j++) {
            int mbase = m0 + wm * 64 + i * 16 + g * 4;
            int n = n0 + wn * 64 + j * 16 + l15;
            if (MODE == 0) {
                int h = n >> 6, d = n & 63;
                if (blockIdx.z < 2) {
                    int f = d >> 1;
                    float sgn = (d & 1) ? 1.f : -1.f;
                    float sc = (blockIdx.z == 0) ? SCALE_L2E : 1.0f;
                    for (int r = 0; r < 4; r++) {
                        int m = mbase + r;
                        int b = m >> 11, s = m & 2047;
                        float v = acc[i][j][r];
                        float p = __shfl_xor(v, 1);
                        float2 cs = tab[s * 32 + f];
                        float out = (v * cs.x + p * cs.y * sgn) * sc;
                        Dst[(((size_t)(b * NH + h)) * S_LEN + s) * DH + d] =
                            f2bf(out);
                    }
                } else {
                    for (int r = 0; r < 4; r++) {
                        int m = mbase + r;
                        int b = m >> 11, s = m & 2047;
                        Dst[((size_t)(b * NH + h) * DH + d) * S_LEN + s] =
                            f2bf(acc[i][j][r]);
                    }
                }
            } else {
                for (int r = 0; r < 4; r++)
                    Fout[(size_t)(mbase + r) * DM + n] = acc[i][j][r];
            }
        }
    }
}

// ---------------------------------------------------------------- attention
// (verbatim R17 attn_k15) 8-wave key-split, double-buffered KVBLK=128,
// 64KB LDS, 2 blocks/CU via launch_bounds(512,4).
__global__ __launch_bounds__(512, 4) void attn_k15(
    const ushort_t* __restrict__ Q, const ushort_t* __restrict__ K,
    const ushort_t* __restrict__ Vt, ushort_t* __restrict__ O)
{
    __shared__ __attribute__((aligned(16))) ushort_t Ks[2][8192];  // 16KB ea
    __shared__ __attribute__((aligned(16))) ushort_t Vs[2][8192];  // 16KB ea

    int tid = threadIdx.x, wv = tid >> 6, lane = tid & 63;
    int l31 = lane & 31, h = lane >> 5, r7 = l31 & 7;
    int bid = blockIdx.x;
    int u = (bid < 256) ? (15 - (bid >> 5)) : ((bid - 256) >> 5);
    int bh = bid & 31;              // low bits -> XCD affinity for K/V reuse
    int qsub = wv & 3, hf = wv >> 2;
    int qmin = u * 128 + qsub * 32, qmax = qmin + 31;
    int ntr = u + 1;                // 128-key rounds

    const ushort_t* Qp = Q + (size_t)bh * S_LEN * DH;
    const char* Kp = (const char*)(K + (size_t)bh * S_LEN * DH);
    const char* Vp = (const char*)(Vt + (size_t)bh * DH * S_LEN);

    short8 qf[4];
    {
        const ushort_t* qp = Qp + (((size_t)(qmin + l31)) << 6) + h * 8;
        #pragma unroll
        for (int ds = 0; ds < 4; ds++)
            qf[ds] = *reinterpret_cast<const short8*>(qp + ds * 16);
    }

    f32x16 oacc[2];
    oacc[0] = (f32x16){0.f};
    oacc[1] = (f32x16){0.f};
    float m_run = -1e20f, l_run = 0.f;

#define STAGE16(buf, kk0) do {                                                \
    _Pragma("unroll") for (int c_ = 0; c_ < 2; ++c_) {                        \
        int L_ = c_ * 8192 + tid * 16;                                        \
        int rk_ = L_ >> 7;                                                    \
        int ck_ = (L_ & 127) ^ ((rk_ & 7) << 4);                              \
        __builtin_amdgcn_global_load_lds(                                     \
            (glob_t*)(Kp + (size_t)((kk0) + rk_) * 128 + ck_),                \
            (lds_t*)((char*)&Ks[buf][0] + c_ * 8192 + wv * 1024), 16, 0, 0);  \
        int rv_ = L_ >> 8;                                                    \
        int cb_ = L_ & 255;                                                   \
        int cv_ = ((cb_ & 127) ^ ((rv_ & 7) << 4)) | (cb_ & 128);             \
        __builtin_amdgcn_global_load_lds(                                     \
            (glob_t*)(Vp + (size_t)rv_ * (S_LEN * 2) + (size_t)(kk0) * 2      \
                      + cv_),                                                 \
            (lds_t*)((char*)&Vs[buf][0] + c_ * 8192 + wv * 1024), 16, 0, 0);  \
    } } while (0)

    STAGE16(0, 0);
    WAITV0;
    __builtin_amdgcn_s_barrier();

    int buf = 0;
    for (int t = 0; t < ntr; ++t) {
        if (t + 1 < ntr) STAGE16(buf ^ 1, (t + 1) * 128);

        int k0 = t * 128 + hf * 64;
        if (k0 <= qmax) {
            const char* kb = (const char*)&Ks[buf][0];
            const char* vbp = (const char*)&Vs[buf][0];

            f32x16 st[2];
            #pragma unroll
            for (int s = 0; s < 2; s++) {
                short8 kf[4];
                #pragma unroll
                for (int ds = 0; ds < 4; ds++)
                    kf[ds] = *reinterpret_cast<const short8*>(
                        kb + (hf * 64 + s * 32 + l31) * 128
                        + (((h + 2 * ds) ^ r7) << 4));
                __builtin_amdgcn_s_setprio(1);
                f32x16 z = {0.f};
                #pragma unroll
                for (int ds = 0; ds < 4; ds++)
                    z = __builtin_amdgcn_mfma_f32_32x32x16_bf16(
                        kf[ds], qf[ds], z, 0, 0, 0);
                st[s] = z;
                __builtin_amdgcn_s_setprio(0);
            }

            if (k0 + 63 > qmin) {
                int q = qmin + l31;
                #pragma unroll
                for (int s = 0; s < 2; s++)
                    #pragma unroll
                    for (int r = 0; r < 16; r++)
                        if ((k0 + s * 32 + (r & 3) + 8 * (r >> 2) + 4 * h) > q)
                            st[s][r] = -1e30f;
            }

            if (t == 0) {
                float m0v = st[0][0], m1v = st[1][0];
                #pragma unroll
                for (int r = 1; r < 16; r++) {
                    m0v = fmaxf(m0v, st[0][r]);
                    m1v = fmaxf(m1v, st[1][r]);
                }
                float m16 = fmaxf(m0v, m1v);
                m16 = fmaxf(m16, __shfl_xor(m16, 32));
                m_run = m16 + 8.0f;
            }

            float ps = 0.f;
            short4x pa[2][4];
            #pragma unroll
            for (int s = 0; s < 2; s++)
                #pragma unroll
                for (int kt = 0; kt < 4; kt++) {
                    float p0 = exp2f(st[s][4 * kt + 0] - m_run);
                    float p1 = exp2f(st[s][4 * kt + 1] - m_run);
                    float p2 = exp2f(st[s][4 * kt + 2] - m_run);
                    float p3 = exp2f(st[s][4 * kt + 3] - m_run);
                    ps += (p0 + p1) + (p2 + p3);
                    u32x2 w = { (uint_t)f2bf(p0) | ((uint_t)f2bf(p1) << 16),
                                (uint_t)f2bf(p2) | ((uint_t)f2bf(p3) << 16) };
                    pa[s][kt] = __builtin_bit_cast(short4x, w);
                }
            l_run += ps;

            #pragma unroll
            for (int s = 0; s < 2; s++) {
                short4x vb[2][4];
                #pragma unroll
                for (int db = 0; db < 2; db++)
                    #pragma unroll
                    for (int kt = 0; kt < 4; kt++) {
                        int c = s * 4 + kt;   // 16B unit within 128B half
                        vb[db][kt] = *reinterpret_cast<const short4x*>(
                            vbp + (db * 32 + l31) * 256 + hf * 128
                            + (((c ^ r7) & 7) << 4) + h * 8);
                    }
                __builtin_amdgcn_s_setprio(1);
                #pragma unroll
                for (int kt = 0; kt < 4; kt++) {
                    oacc[0] = __builtin_amdgcn_mfma_f32_32x32x8bf16_1k(
                        vb[0][kt], pa[s][kt], oacc[0], 0, 0, 0);
                    oacc[1] = __builtin_amdgcn_mfma_f32_32x32x8bf16_1k(
                        vb[1][kt], pa[s][kt], oacc[1], 0, 0, 0);
                }
                __builtin_amdgcn_s_setprio(0);
            }
        }

        WAITV0;                       // stage(t+1) landed (issued pre-compute)
        __builtin_amdgcn_s_barrier();
        buf ^= 1;
    }

    // ---- cross-wave merge: hf=1 publishes, hf=0 merges + stores (exact)
    {
        float* smK = (float*)&Ks[0][0];        // 32KB scratch (loop done)
        float* smV = (float*)&Vs[0][0];        // 32KB scratch
        float* base = (qsub < 2) ? smK : smV;
        float* slot = base + ((qsub & 1) * 64 + lane) * 34;
        if (hf == 1) {
            #pragma unroll
            for (int j = 0; j < 16; j++) slot[j] = oacc[0][j];
            #pragma unroll
            for (int j = 0; j < 16; j++) slot[16 + j] = oacc[1][j];
            slot[32] = l_run;
            slot[33] = m_run;
        }
        __syncthreads();
        if (hf == 0) {
            float lB = slot[32], mB = slot[33];
            float ms = fmaxf(m_run, mB);
            float fa = exp2f(m_run - ms), fb = exp2f(mB - ms);
            float l_tot = l_run * fa + lB * fb;
            l_tot += __shfl_xor(l_tot, 32);
            float inv = 1.0f / l_tot;
            int b = bh >> 4, head = bh & 15;
            int q_row = qmin + l31;
            size_t obase = ((size_t)b * S_LEN + q_row) * DM + head * DH;
            #pragma unroll
            for (int db = 0; db < 2; db++)
                #pragma unroll
                for (int rg = 0; rg < 4; rg++) {
                    u16x4 o;
                    #pragma unroll
                    for (int j = 0; j < 4; j++) {
                        float v = oacc[db][rg * 4 + j] * fa
                                + slot[db * 16 + rg * 4 + j] * fb;
                        o[j] = f2bf(v * inv);
                    }
                    *reinterpret_cast<u16x4*>(
                        &O[obase + db * 32 + rg * 8 + h * 4]) = o;
                }
        }
    }
#undef STAGE16
}

// ---------------------------------------------------------------- launch
extern "C" void kernel_launch(void* const* d_in, const int* in_sizes, int n_in,
                              void* d_out, int out_size, void* d_ws, size_t ws_size,
                              hipStream_t stream)
{
    const float* X  = (const float*)d_in[0];
    const int* pos  = (const int*)d_in[1];
    const float* qw = (const float*)d_in[2];
    const float* kw = (const float*)d_in[3];
    const float* vw = (const float*)d_in[4];
    const float* ow = (const float*)d_in[5];
    float* out = (float*)d_out;

    char* ws = (char*)d_ws;
    ushort_t* Xb   = (ushort_t*)(ws);               // 8 MB X bf16
    ushort_t* Wqb  = (ushort_t*)(ws + 8388608);     // 2 MB (W3 base)
    ushort_t* Wkb  = (ushort_t*)(ws + 10485760);    // 2 MB (W3 contiguous)
    ushort_t* Wvb  = (ushort_t*)(ws + 12582912);    // 2 MB (W3 contiguous)
    ushort_t* Wob  = (ushort_t*)(ws + 14680064);    // 2 MB
    ushort_t* Qbh  = (ushort_t*)(ws + 16777216);    // 8 MB [BH][S][64]
    ushort_t* Kbh  = (ushort_t*)(ws + 25165824);    // 8 MB
    ushort_t* Vtb  = (ushort_t*)(ws + 41943040);    // 8 MB [BH][64][S]
    ushort_t* AttO = (ushort_t*)(ws + 50331648);    // 8 MB [B][S][1024]
    float2*   tab  = (float2*)(ws + 58720256);      // 0.5 MB

    prep_all<<<8448, 256, 0, stream>>>(X, qw, kw, vw, ow, pos,
                                       Xb, Wqb, Wkb, Wvb, Wob, tab);
    qkv8_gemm<<<dim3(16, 12), 512, 0, stream>>>(
        Xb, Wqb, Qbh, Kbh, Vtb, tab);
    attn_k15<<<512, 512, 0, stream>>>(Qbh, Kbh, Vtb, AttO);
    gemm128b<1><<<dim3(32, 8, 1), 256, 0, stream>>>(
        AttO, Wob, nullptr, nullptr, nullptr, nullptr, nullptr, out, tab);
}

// Round 21
// 118.905 us; speedup vs baseline: 1.0576x; 1.0544x over previous
//
#include <hip/hip_runtime.h>
#include <hip/hip_bf16.h>

typedef unsigned short ushort_t;
typedef unsigned int uint_t;
typedef __attribute__((ext_vector_type(4))) float f32x4;
typedef __attribute__((ext_vector_type(16))) float f32x16;
typedef __attribute__((ext_vector_type(8))) short short8;
typedef __attribute__((ext_vector_type(4))) short short4x;
typedef __attribute__((ext_vector_type(4))) unsigned short u16x4;
typedef __attribute__((ext_vector_type(2))) uint_t u32x2;

typedef const __attribute__((address_space(1))) unsigned char glob_t;
typedef __attribute__((address_space(3))) unsigned char lds_t;

#define S_LEN 2048
#define DM 1024
#define NH 16
#define DH 64
#define NB 2
#define BH (NB*NH)          // 32
#define MROWS (NB*S_LEN)    // 4096

#define SCALE_L2E 0.18033688f   /* 0.125 * log2(e) — folded into Q */

__device__ __forceinline__ float bf2f(ushort_t u) {
    return __uint_as_float(((uint_t)u) << 16);
}
__device__ __forceinline__ ushort_t f2bf(float f) {
    __hip_bfloat16 h = __float2bfloat16(f);
    return *reinterpret_cast<ushort_t*>(&h);
}

#define WAITV0 asm volatile("s_waitcnt vmcnt(0)" ::: "memory")

// ---------------------------------------------------------------- prep
__global__ __launch_bounds__(256) void prep_all(
    const float* __restrict__ X,  const float* __restrict__ Wq,
    const float* __restrict__ Wk, const float* __restrict__ Wv,
    const float* __restrict__ Wo, const int* __restrict__ pos,
    ushort_t* __restrict__ Xb,  ushort_t* __restrict__ Wqb,
    ushort_t* __restrict__ Wkb, ushort_t* __restrict__ Wvb,
    ushort_t* __restrict__ Wob, float2* __restrict__ tab)
{
    int bid = blockIdx.x;
    if (bid < 8192) {
        size_t i = (size_t)bid * 256 + threadIdx.x;
        size_t e = i * 4;
        const float* src; ushort_t* dst; size_t off;
        if (e < (size_t)MROWS * DM) { src = X; dst = Xb; off = e; }
        else {
            size_t r = e - (size_t)MROWS * DM;
            int w = (int)(r >> 20); off = r & 1048575;
            src = (w == 0) ? Wq : (w == 1) ? Wk : (w == 2) ? Wv : Wo;
            dst = (w == 0) ? Wqb : (w == 1) ? Wkb : (w == 2) ? Wvb : Wob;
        }
        float4 v = *reinterpret_cast<const float4*>(src + off);
        u16x4 o;
        o[0] = f2bf(v.x); o[1] = f2bf(v.y); o[2] = f2bf(v.z); o[3] = f2bf(v.w);
        *reinterpret_cast<u16x4*>(dst + off) = o;
    } else {
        int i = (bid - 8192) * 256 + threadIdx.x;   // 65536
        int s = i >> 5, f = i & 31;
        float inv = powf(10000.0f, -(float)f / 32.0f);
        float ang = (float)pos[s] * inv;
        tab[i] = make_float2(cosf(ang), sinf(ang));
    }
}

// ---------------------------------------------------------------- GEMM
// (verbatim R11 gemm128b) C[m][n] = sum_k A[m][k]*W[n][k]; BK=32,
// m97-style global_load_lds staging, linear LDS.
// MODE 0: QKV (z picks W/dst; z<2 fused RoPE; z==2 transposed V scatter)
// MODE 1: fp32 row-major out (O-proj)
template<int MODE>
__global__ __launch_bounds__(256) void gemm128b(
    const ushort_t* __restrict__ A,
    const ushort_t* __restrict__ W0, const ushort_t* __restrict__ W1,
    const ushort_t* __restrict__ W2,
    ushort_t* __restrict__ D0, ushort_t* __restrict__ D1,
    ushort_t* __restrict__ D2,
    float* __restrict__ Fout, const float2* __restrict__ tab)
{
    __shared__ __attribute__((aligned(16))) ushort_t As[128 * 32];
    __shared__ __attribute__((aligned(16))) ushort_t Bs[128 * 32];
    const ushort_t* W = (MODE == 1 || blockIdx.z == 0) ? W0
                        : (blockIdx.z == 1 ? W1 : W2);
    ushort_t* Dst = (blockIdx.z == 0) ? D0 : (blockIdx.z == 1) ? D1 : D2;
    int m0 = blockIdx.x * 128, n0 = blockIdx.y * 128;
    int tid = threadIdx.x, lane = tid & 63, wv = tid >> 6;
    int wm = wv >> 1, wn = wv & 1;
    int l15 = lane & 15, g = lane >> 4;

    f32x4 acc[4][4];
    for (int i = 0; i < 4; i++)
        for (int j = 0; j < 4; j++)
            acc[i][j] = (f32x4){0.f, 0.f, 0.f, 0.f};

    int srow = wv * 32 + (lane >> 2);
    int scol = (lane & 3) * 8;
    const ushort_t* Ap = A + (size_t)(m0 + srow) * DM + scol;
    const ushort_t* Wp = W + (size_t)(n0 + srow) * DM + scol;
    lds_t* laA0 = (lds_t*)&As[wv * 1024];
    lds_t* laA1 = (lds_t*)&As[wv * 1024 + 512];
    lds_t* laB0 = (lds_t*)&Bs[wv * 1024];
    lds_t* laB1 = (lds_t*)&Bs[wv * 1024 + 512];

    for (int kk = 0; kk < DM; kk += 32) {
        __builtin_amdgcn_global_load_lds((glob_t*)(Ap + kk), laA0, 16, 0, 0);
        __builtin_amdgcn_global_load_lds((glob_t*)(Ap + 16 * DM + kk), laA1, 16, 0, 0);
        __builtin_amdgcn_global_load_lds((glob_t*)(Wp + kk), laB0, 16, 0, 0);
        __builtin_amdgcn_global_load_lds((glob_t*)(Wp + 16 * DM + kk), laB1, 16, 0, 0);
        __syncthreads();
        short8 af[4], bf[4];
        for (int i = 0; i < 4; i++)
            af[i] = *reinterpret_cast<const short8*>(
                &As[(wm * 64 + i * 16 + l15) * 32 + g * 8]);
        for (int j = 0; j < 4; j++)
            bf[j] = *reinterpret_cast<const short8*>(
                &Bs[(wn * 64 + j * 16 + l15) * 32 + g * 8]);
        __builtin_amdgcn_s_setprio(1);
        for (int i = 0; i < 4; i++)
            for (int j = 0; j < 4; j++)
                acc[i][j] = __builtin_amdgcn_mfma_f32_16x16x32_bf16(
                    af[i], bf[j], acc[i][j], 0, 0, 0);
        __builtin_amdgcn_s_setprio(0);
        __syncthreads();
    }

    for (int i = 0; i < 4; i++) {
        for (int j = 0; j < 4; j++) {
            int mbase = m0 + wm * 64 + i * 16 + g * 4;
            int n = n0 + wn * 64 + j * 16 + l15;
            if (MODE == 0) {
                int h = n >> 6, d = n & 63;
                if (blockIdx.z < 2) {
                    int f = d >> 1;
                    float sgn = (d & 1) ? 1.f : -1.f;
                    float sc = (blockIdx.z == 0) ? SCALE_L2E : 1.0f;
                    for (int r = 0; r < 4; r++) {
                        int m = mbase + r;
                        int b = m >> 11, s = m & 2047;
                        float v = acc[i][j][r];
                        float p = __shfl_xor(v, 1);
                        float2 cs = tab[s * 32 + f];
                        float out = (v * cs.x + p * cs.y * sgn) * sc;
                        Dst[(((size_t)(b * NH + h)) * S_LEN + s) * DH + d] =
                            f2bf(out);
                    }
                } else {
                    for (int r = 0; r < 4; r++) {
                        int m = mbase + r;
                        int b = m >> 11, s = m & 2047;
                        Dst[((size_t)(b * NH + h) * DH + d) * S_LEN + s] =
                            f2bf(acc[i][j][r]);
                    }
                }
            } else {
                for (int r = 0; r < 4; r++)
                    Fout[(size_t)(mbase + r) * DM + n] = acc[i][j][r];
            }
        }
    }
}

// ---------------------------------------------------------------- attention
// (verbatim R17 attn_k15 — best measured: 52.6 us) 8-wave key-split,
// double-buffered KVBLK=128, 64KB LDS, 2 blocks/CU via launch_bounds(512,4).
// Block = (bh, u) 128-q tile; wave = (q-subtile wv&3, 64-key half wv>>2).
// Constant pair-sum grid; freeze-max at first computed tile (margin 8);
// exact cross-wave merge of key-half partials in the epilogue.
__global__ __launch_bounds__(512, 4) void attn_k15(
    const ushort_t* __restrict__ Q, const ushort_t* __restrict__ K,
    const ushort_t* __restrict__ Vt, ushort_t* __restrict__ O)
{
    __shared__ __attribute__((aligned(16))) ushort_t Ks[2][8192];  // 16KB ea
    __shared__ __attribute__((aligned(16))) ushort_t Vs[2][8192];  // 16KB ea

    int tid = threadIdx.x, wv = tid >> 6, lane = tid & 63;
    int l31 = lane & 31, h = lane >> 5, r7 = l31 & 7;
    int bid = blockIdx.x;
    int u = (bid < 256) ? (15 - (bid >> 5)) : ((bid - 256) >> 5);
    int bh = bid & 31;              // low bits -> XCD affinity for K/V reuse
    int qsub = wv & 3, hf = wv >> 2;
    int qmin = u * 128 + qsub * 32, qmax = qmin + 31;
    int ntr = u + 1;                // 128-key rounds

    const ushort_t* Qp = Q + (size_t)bh * S_LEN * DH;
    const char* Kp = (const char*)(K + (size_t)bh * S_LEN * DH);
    const char* Vp = (const char*)(Vt + (size_t)bh * DH * S_LEN);

    short8 qf[4];
    {
        const ushort_t* qp = Qp + (((size_t)(qmin + l31)) << 6) + h * 8;
        #pragma unroll
        for (int ds = 0; ds < 4; ds++)
            qf[ds] = *reinterpret_cast<const short8*>(qp + ds * 16);
    }

    f32x16 oacc[2];
    oacc[0] = (f32x16){0.f};
    oacc[1] = (f32x16){0.f};
    float m_run = -1e20f, l_run = 0.f;

#define STAGE16(buf, kk0) do {                                                \
    _Pragma("unroll") for (int c_ = 0; c_ < 2; ++c_) {                        \
        int L_ = c_ * 8192 + tid * 16;                                        \
        int rk_ = L_ >> 7;                                                    \
        int ck_ = (L_ & 127) ^ ((rk_ & 7) << 4);                              \
        __builtin_amdgcn_global_load_lds(                                     \
            (glob_t*)(Kp + (size_t)((kk0) + rk_) * 128 + ck_),                \
            (lds_t*)((char*)&Ks[buf][0] + c_ * 8192 + wv * 1024), 16, 0, 0);  \
        int rv_ = L_ >> 8;                                                    \
        int cb_ = L_ & 255;                                                   \
        int cv_ = ((cb_ & 127) ^ ((rv_ & 7) << 4)) | (cb_ & 128);             \
        __builtin_amdgcn_global_load_lds(                                     \
            (glob_t*)(Vp + (size_t)rv_ * (S_LEN * 2) + (size_t)(kk0) * 2      \
                      + cv_),                                                 \
            (lds_t*)((char*)&Vs[buf][0] + c_ * 8192 + wv * 1024), 16, 0, 0);  \
    } } while (0)

    STAGE16(0, 0);
    WAITV0;
    __builtin_amdgcn_s_barrier();

    int buf = 0;
    for (int t = 0; t < ntr; ++t) {
        if (t + 1 < ntr) STAGE16(buf ^ 1, (t + 1) * 128);

        int k0 = t * 128 + hf * 64;
        if (k0 <= qmax) {
            const char* kb = (const char*)&Ks[buf][0];
            const char* vbp = (const char*)&Vs[buf][0];

            f32x16 st[2];
            #pragma unroll
            for (int s = 0; s < 2; s++) {
                short8 kf[4];
                #pragma unroll
                for (int ds = 0; ds < 4; ds++)
                    kf[ds] = *reinterpret_cast<const short8*>(
                        kb + (hf * 64 + s * 32 + l31) * 128
                        + (((h + 2 * ds) ^ r7) << 4));
                __builtin_amdgcn_s_setprio(1);
                f32x16 z = {0.f};
                #pragma unroll
                for (int ds = 0; ds < 4; ds++)
                    z = __builtin_amdgcn_mfma_f32_32x32x16_bf16(
                        kf[ds], qf[ds], z, 0, 0, 0);
                st[s] = z;
                __builtin_amdgcn_s_setprio(0);
            }

            if (k0 + 63 > qmin) {
                int q = qmin + l31;
                #pragma unroll
                for (int s = 0; s < 2; s++)
                    #pragma unroll
                    for (int r = 0; r < 16; r++)
                        if ((k0 + s * 32 + (r & 3) + 8 * (r >> 2) + 4 * h) > q)
                            st[s][r] = -1e30f;
            }

            if (t == 0) {
                float m0v = st[0][0], m1v = st[1][0];
                #pragma unroll
                for (int r = 1; r < 16; r++) {
                    m0v = fmaxf(m0v, st[0][r]);
                    m1v = fmaxf(m1v, st[1][r]);
                }
                float m16 = fmaxf(m0v, m1v);
                m16 = fmaxf(m16, __shfl_xor(m16, 32));
                m_run = m16 + 8.0f;
            }

            float ps = 0.f;
            short4x pa[2][4];
            #pragma unroll
            for (int s = 0; s < 2; s++)
                #pragma unroll
                for (int kt = 0; kt < 4; kt++) {
                    float p0 = exp2f(st[s][4 * kt + 0] - m_run);
                    float p1 = exp2f(st[s][4 * kt + 1] - m_run);
                    float p2 = exp2f(st[s][4 * kt + 2] - m_run);
                    float p3 = exp2f(st[s][4 * kt + 3] - m_run);
                    ps += (p0 + p1) + (p2 + p3);
                    u32x2 w = { (uint_t)f2bf(p0) | ((uint_t)f2bf(p1) << 16),
                                (uint_t)f2bf(p2) | ((uint_t)f2bf(p3) << 16) };
                    pa[s][kt] = __builtin_bit_cast(short4x, w);
                }
            l_run += ps;

            #pragma unroll
            for (int s = 0; s < 2; s++) {
                short4x vb[2][4];
                #pragma unroll
                for (int db = 0; db < 2; db++)
                    #pragma unroll
                    for (int kt = 0; kt < 4; kt++) {
                        int c = s * 4 + kt;   // 16B unit within 128B half
                        vb[db][kt] = *reinterpret_cast<const short4x*>(
                            vbp + (db * 32 + l31) * 256 + hf * 128
                            + (((c ^ r7) & 7) << 4) + h * 8);
                    }
                __builtin_amdgcn_s_setprio(1);
                #pragma unroll
                for (int kt = 0; kt < 4; kt++) {
                    oacc[0] = __builtin_amdgcn_mfma_f32_32x32x8bf16_1k(
                        vb[0][kt], pa[s][kt], oacc[0], 0, 0, 0);
                    oacc[1] = __builtin_amdgcn_mfma_f32_32x32x8bf16_1k(
                        vb[1][kt], pa[s][kt], oacc[1], 0, 0, 0);
                }
                __builtin_amdgcn_s_setprio(0);
            }
        }

        WAITV0;                       // stage(t+1) landed (issued pre-compute)
        __builtin_amdgcn_s_barrier();
        buf ^= 1;
    }

    // ---- cross-wave merge: hf=1 publishes, hf=0 merges + stores (exact)
    {
        float* smK = (float*)&Ks[0][0];        // 32KB scratch (loop done)
        float* smV = (float*)&Vs[0][0];        // 32KB scratch
        float* base = (qsub < 2) ? smK : smV;
        float* slot = base + ((qsub & 1) * 64 + lane) * 34;
        if (hf == 1) {
            #pragma unroll
            for (int j = 0; j < 16; j++) slot[j] = oacc[0][j];
            #pragma unroll
            for (int j = 0; j < 16; j++) slot[16 + j] = oacc[1][j];
            slot[32] = l_run;
            slot[33] = m_run;
        }
        __syncthreads();
        if (hf == 0) {
            float lB = slot[32], mB = slot[33];
            float ms = fmaxf(m_run, mB);
            float fa = exp2f(m_run - ms), fb = exp2f(mB - ms);
            float l_tot = l_run * fa + lB * fb;
            l_tot += __shfl_xor(l_tot, 32);
            float inv = 1.0f / l_tot;
            int b = bh >> 4, head = bh & 15;
            int q_row = qmin + l31;
            size_t obase = ((size_t)b * S_LEN + q_row) * DM + head * DH;
            #pragma unroll
            for (int db = 0; db < 2; db++)
                #pragma unroll
                for (int rg = 0; rg < 4; rg++) {
                    u16x4 o;
                    #pragma unroll
                    for (int j = 0; j < 4; j++) {
                        float v = oacc[db][rg * 4 + j] * fa
                                + slot[db * 16 + rg * 4 + j] * fb;
                        o[j] = f2bf(v * inv);
                    }
                    *reinterpret_cast<u16x4*>(
                        &O[obase + db * 32 + rg * 8 + h * 4]) = o;
                }
        }
    }
#undef STAGE16
}

// ---------------------------------------------------------------- launch
extern "C" void kernel_launch(void* const* d_in, const int* in_sizes, int n_in,
                              void* d_out, int out_size, void* d_ws, size_t ws_size,
                              hipStream_t stream)
{
    const float* X  = (const float*)d_in[0];
    const int* pos  = (const int*)d_in[1];
    const float* qw = (const float*)d_in[2];
    const float* kw = (const float*)d_in[3];
    const float* vw = (const float*)d_in[4];
    const float* ow = (const float*)d_in[5];
    float* out = (float*)d_out;

    char* ws = (char*)d_ws;
    ushort_t* Xb   = (ushort_t*)(ws);               // 8 MB X bf16
    ushort_t* Wqb  = (ushort_t*)(ws + 8388608);     // 2 MB
    ushort_t* Wkb  = (ushort_t*)(ws + 10485760);    // 2 MB
    ushort_t* Wvb  = (ushort_t*)(ws + 12582912);    // 2 MB
    ushort_t* Wob  = (ushort_t*)(ws + 14680064);    // 2 MB
    ushort_t* Qbh  = (ushort_t*)(ws + 16777216);    // 8 MB [BH][S][64]
    ushort_t* Kbh  = (ushort_t*)(ws + 25165824);    // 8 MB
    ushort_t* Vtb  = (ushort_t*)(ws + 41943040);    // 8 MB [BH][64][S]
    ushort_t* AttO = (ushort_t*)(ws + 50331648);    // 8 MB [B][S][1024]
    float2*   tab  = (float2*)(ws + 58720256);      // 0.5 MB

    prep_all<<<8448, 256, 0, stream>>>(X, qw, kw, vw, ow, pos,
                                       Xb, Wqb, Wkb, Wvb, Wob, tab);
    gemm128b<0><<<dim3(32, 8, 3), 256, 0, stream>>>(
        Xb, Wqb, Wkb, Wvb, Qbh, Kbh, Vtb, nullptr, tab);
    attn_k15<<<512, 512, 0, stream>>>(Qbh, Kbh, Vtb, AttO);
    gemm128b<1><<<dim3(32, 8, 1), 256, 0, stream>>>(
        AttO, Wob, nullptr, nullptr, nullptr, nullptr, nullptr, out, tab);
}